// Round 8
// baseline (495.669 us; speedup 1.0000x reference)
//
#include <hip/hip_runtime.h>
#include <hip/hip_cooperative_groups.h>

namespace cg = cooperative_groups;

// Problem constants (from reference)
#define D_H     512
#define D_MODEL 2048
#define B_      4
#define T_      4096
// T_*D_MODEL = 2^23  (for the >>23 / &2047 index tricks below)

typedef float vfloat4 __attribute__((ext_vector_type(4)));
typedef float vfloat2 __attribute__((ext_vector_type(2)));

// ---------------------------------------------------------------------------
// One split-K GEMV slice: out[b][j] += sum_{k in slice} x[b][k]*W[k][j], b<4.
// 1 column/thread, scalar W loads (wave reads 256 B contiguous), LDS x bcast.
// Same slice counts as the verified 282-µs version -> same rounding profile.
// ---------------------------------------------------------------------------
template <int KCHUNK>
__device__ __forceinline__ void gemv_slice(
        const float* __restrict__ x, const float* __restrict__ W,
        float* __restrict__ out, int K, int N, int jb, int kb, int tid) {
    __shared__ float xs[4][KCHUNK];
    const int j  = jb * 256 + tid;
    const int k0 = kb * KCHUNK;
    for (int i = tid; i < 4 * KCHUNK; i += 256) {
        int b = i / KCHUNK, k = i - b * KCHUNK;
        xs[b][k] = x[b * K + k0 + k];
    }
    __syncthreads();
    float a0 = 0.f, a1 = 0.f, a2 = 0.f, a3 = 0.f;
    const float* Wp = W + (long)k0 * N + j;
#pragma unroll 8
    for (int k = 0; k < KCHUNK; ++k) {
        float w = Wp[(long)k * N];
        a0 = fmaf(xs[0][k], w, a0);
        a1 = fmaf(xs[1][k], w, a1);
        a2 = fmaf(xs[2][k], w, a2);
        a3 = fmaf(xs[3][k], w, a3);
    }
    atomicAdd(&out[0 * N + j], a0);
    atomicAdd(&out[1 * N + j], a1);
    atomicAdd(&out[2 * N + j], a2);
    atomicAdd(&out[3 * N + j], a3);
}

// ---------------------------------------------------------------------------
// Fused cooperative kernel: zero -> GEMV1 -> GEMV2 -> GEMV3 -> stream.
// 512 blocks x 256 threads (2 blocks/CU, co-residency safe at any VGPR count).
// Removes: memset dispatch, 4 launch gaps, inter-launch drains.
// ---------------------------------------------------------------------------
__global__ __launch_bounds__(256) void fused_bridge(
        const float* __restrict__ lh, const float* __restrict__ zH,
        const float* __restrict__ W_mem, const float* __restrict__ W_v,
        const float* __restrict__ W_o, const float* __restrict__ gate,
        float* __restrict__ out, float* __restrict__ ws) {
    const int tid  = threadIdx.x;
    const int bid  = blockIdx.x;
    const int gtid = bid * 256 + tid;          // 0 .. 131071
    float* mem = ws;
    float* V   = ws + B_ * D_MODEL;
    float* r   = ws + 2 * B_ * D_MODEL;
    cg::grid_group grid = cg::this_grid();

    // P0: zero the three 4x2048 accumulators (24576 floats)
    if (gtid < 3 * B_ * D_MODEL) ws[gtid] = 0.f;
    grid.sync();

    // P1: mem = zH @ W_mem   (K=512, 32 slices x KCHUNK=16; 256 active blocks)
    if (bid < 256) gemv_slice<16>(zH, W_mem, mem, D_H, D_MODEL, bid & 7, bid >> 3, tid);
    grid.sync();

    // P2: V = mem @ W_v      (K=2048, 64 slices x KCHUNK=32; all 512 blocks)
    gemv_slice<32>(mem, W_v, V, D_MODEL, D_MODEL, bid & 7, bid >> 3, tid);
    grid.sync();

    // P3: r = V @ W_o
    gemv_slice<32>(V, W_o, r, D_MODEL, D_MODEL, bid & 7, bid >> 3, tid);
    grid.sync();

    // P4: out = lh + sigmoid(gate) * r  (268 MB stream; 64 iters/thread exact)
    const float g = gate[0];
    const float s = 1.0f / (1.0f + __expf(-g));
    const vfloat4* lh4 = reinterpret_cast<const vfloat4*>(lh);
    vfloat4* out4 = reinterpret_cast<vfloat4*>(out);
#pragma unroll 4
    for (int it = 0; it < 64; ++it) {
        long i  = (long)gtid + (long)it * (512 * 256);
        long e0 = i * 4;
        int  b  = (int)(e0 >> 23);             // / (T_*D_MODEL)
        int  d  = (int)(e0 & (D_MODEL - 1));   // col within row (4-aligned)
        vfloat4 rv = *reinterpret_cast<const vfloat4*>(r + b * D_MODEL + d);
        vfloat4 v  = __builtin_nontemporal_load(lh4 + i);
        vfloat4 o;
        o.x = fmaf(s, rv.x, v.x);
        o.y = fmaf(s, rv.y, v.y);
        o.z = fmaf(s, rv.z, v.z);
        o.w = fmaf(s, rv.w, v.w);
        __builtin_nontemporal_store(o, out4 + i);
    }
}

// ---------------------------------------------------------------------------
// Fallback path (5 dispatches) in case cooperative launch is rejected under
// graph capture. Same kernels as the verified 286-µs version.
// ---------------------------------------------------------------------------
template <int KCHUNK>
__global__ __launch_bounds__(256) void gemv4_splitk(
        const float* __restrict__ x, const float* __restrict__ W,
        float* __restrict__ out, int K, int N) {
    gemv_slice<KCHUNK>(x, W, out, K, N, (int)blockIdx.x, (int)blockIdx.y,
                       (int)threadIdx.x);
}

__global__ __launch_bounds__(256) void broadcast_add(
        const vfloat4* __restrict__ lh, const float* __restrict__ r,
        const float* __restrict__ gate, vfloat4* __restrict__ out,
        long nchunks) {
    float g = gate[0];
    float s = 1.0f / (1.0f + __expf(-g));
    const long stride = (long)gridDim.x * blockDim.x;
    for (long i = (long)blockIdx.x * blockDim.x + threadIdx.x;
         i < nchunks; i += stride) {
        long e0 = i * 4;
        int  b  = (int)(e0 >> 23);
        int  d  = (int)(e0 & (D_MODEL - 1));
        vfloat4 rv = *reinterpret_cast<const vfloat4*>(r + b * D_MODEL + d);
        vfloat4 v  = __builtin_nontemporal_load(lh + i);
        vfloat4 o;
        o.x = fmaf(s, rv.x, v.x);
        o.y = fmaf(s, rv.y, v.y);
        o.z = fmaf(s, rv.z, v.z);
        o.w = fmaf(s, rv.w, v.w);
        __builtin_nontemporal_store(o, out + i);
    }
}

extern "C" void kernel_launch(void* const* d_in, const int* in_sizes, int n_in,
                              void* d_out, int out_size, void* d_ws, size_t ws_size,
                              hipStream_t stream) {
    const float* lh    = (const float*)d_in[0];
    const float* zH    = (const float*)d_in[1];
    const float* W_mem = (const float*)d_in[2];
    // d_in[3] = W_q, d_in[4] = W_k  -- provably unused: softmax over a
    // length-1 axis is identically 1, so output is independent of Q and K.
    const float* W_v   = (const float*)d_in[5];
    const float* W_o   = (const float*)d_in[6];
    const float* gate  = (const float*)d_in[7];
    float* out = (float*)d_out;
    float* ws  = (float*)d_ws;

    // --- primary: single fused cooperative kernel ---
    {
        void* args[] = {(void*)&lh, (void*)&zH, (void*)&W_mem, (void*)&W_v,
                        (void*)&W_o, (void*)&gate, (void*)&out, (void*)&ws};
        hipError_t e = hipLaunchCooperativeKernel((const void*)fused_bridge,
                                                  dim3(512), dim3(256),
                                                  args, 0, stream);
        if (e == hipSuccess) return;
        (void)hipGetLastError();   // clear sticky error, fall through
    }

    // --- fallback: 5-dispatch path ---
    float* mem = ws;
    float* V   = mem + B_ * D_MODEL;
    float* r   = V   + B_ * D_MODEL;
    (void)hipMemsetAsync(d_ws, 0, (size_t)3 * B_ * D_MODEL * sizeof(float), stream);

    dim3 blk(256);
    {   // Stage 1: mem = zH @ W_mem
        dim3 grd(D_MODEL / 256, 32);
        gemv4_splitk<16><<<grd, blk, 0, stream>>>(zH, W_mem, mem, D_H, D_MODEL);
    }
    {   // Stage 2: V = mem @ W_v
        dim3 grd(D_MODEL / 256, 64);
        gemv4_splitk<32><<<grd, blk, 0, stream>>>(mem, W_v, V, D_MODEL, D_MODEL);
    }
    {   // Stage 3: r = V @ W_o
        dim3 grd(D_MODEL / 256, 64);
        gemv4_splitk<32><<<grd, blk, 0, stream>>>(V, W_o, r, D_MODEL, D_MODEL);
    }
    {   // Stage 4: out = lh + sigmoid(gate) * r
        long nchunks = (long)B_ * T_ * D_MODEL / 4;
        dim3 grd(2048);
        broadcast_add<<<grd, blk, 0, stream>>>(
            (const vfloat4*)lh, r, gate, (vfloat4*)out, nchunks);
    }
}

// Round 9
// 281.478 us; speedup vs baseline: 1.7609x; 1.7609x over previous
//
#include <hip/hip_runtime.h>
#include <hip/hip_bf16.h>

// Problem constants (from reference)
#define D_H     512
#define D_MODEL 2048
#define B_      4
#define T_      4096
// T_*D_MODEL = 2^23  (for the >>23 / &2047 index tricks below)

// Native clang vector (works with __builtin_nontemporal_*; same layout as float4)
typedef float vfloat4 __attribute__((ext_vector_type(4)));

// out[b][j] += sum_{k in slice} x[b][k] * W[k][j]   for all b in [0,4)
// One W element is loaded ONCE and FMA'd into 4 batch accumulators.
// x: (4 x K) fp32; W: (K x N) fp32 row-major; out: (4 x N) fp32 (pre-zeroed)
template <int KCHUNK>
__global__ void gemv4_splitk(const float* __restrict__ x,
                             const float* __restrict__ W,
                             float* __restrict__ out,
                             int K, int N) {
    __shared__ float xs[4][KCHUNK];
    const int tid = threadIdx.x;
    const int j   = blockIdx.x * blockDim.x + tid;    // output column
    const int k0  = blockIdx.y * KCHUNK;              // K-slice start

    for (int i = tid; i < 4 * KCHUNK; i += blockDim.x) {
        int b = i / KCHUNK, k = i - b * KCHUNK;
        xs[b][k] = x[b * K + k0 + k];
    }
    __syncthreads();

    float a0 = 0.f, a1 = 0.f, a2 = 0.f, a3 = 0.f;
    const float* Wp = W + (long)k0 * N + j;
#pragma unroll 8
    for (int k = 0; k < KCHUNK; ++k) {
        float w = Wp[(long)k * N];                    // wave reads 256B contiguous
        a0 = fmaf(xs[0][k], w, a0);                   // xs[b][k]: same addr all lanes -> broadcast
        a1 = fmaf(xs[1][k], w, a1);
        a2 = fmaf(xs[2][k], w, a2);
        a3 = fmaf(xs[3][k], w, a3);
    }
    atomicAdd(&out[0 * N + j], a0);
    atomicAdd(&out[1 * N + j], a1);
    atomicAdd(&out[2 * N + j], a2);
    atomicAdd(&out[3 * N + j], a3);
}

// out[b,t,:] = lh[b,t,:] + sigmoid(gate) * r[b,:]
// 4 fp32 (16 B) per thread; lh/out are zero-reuse streams -> nontemporal.
__global__ void broadcast_add(const vfloat4* __restrict__ lh,
                              const float* __restrict__ r,
                              const float* __restrict__ gate,
                              vfloat4* __restrict__ out) {
    long i = (long)blockIdx.x * blockDim.x + threadIdx.x;

    float g = gate[0];
    float s = 1.0f / (1.0f + __expf(-g));

    long e0 = i * 4;
    int  b  = (int)(e0 >> 23);             // / (T_*D_MODEL)
    int  d  = (int)(e0 & (D_MODEL - 1));   // col within row (4-aligned)

    vfloat4 rv = *reinterpret_cast<const vfloat4*>(r + b * D_MODEL + d);  // L2-resident
    vfloat4 v  = __builtin_nontemporal_load(lh + i);

    vfloat4 o;
    o.x = fmaf(s, rv.x, v.x);
    o.y = fmaf(s, rv.y, v.y);
    o.z = fmaf(s, rv.z, v.z);
    o.w = fmaf(s, rv.w, v.w);
    __builtin_nontemporal_store(o, out + i);
}

extern "C" void kernel_launch(void* const* d_in, const int* in_sizes, int n_in,
                              void* d_out, int out_size, void* d_ws, size_t ws_size,
                              hipStream_t stream) {
    const float* lh    = (const float*)d_in[0];
    const float* zH    = (const float*)d_in[1];
    const float* W_mem = (const float*)d_in[2];
    // d_in[3] = W_q, d_in[4] = W_k  -- provably unused: softmax over a
    // length-1 axis is identically 1, so output is independent of Q and K.
    const float* W_v   = (const float*)d_in[5];
    const float* W_o   = (const float*)d_in[6];
    const float* gate  = (const float*)d_in[7];
    float* out = (float*)d_out;

    // fp32 workspace: mem(4 x D), V(4 x D), r(4 x D)
    float* mem = (float*)d_ws;
    float* V   = mem + B_ * D_MODEL;
    float* r   = V   + B_ * D_MODEL;
    (void)hipMemsetAsync(d_ws, 0, (size_t)3 * B_ * D_MODEL * sizeof(float), stream);

    dim3 blk(256);

    // Stage 1: mem = zH @ W_mem   (K=512,  32 slices x 16)
    {
        dim3 grd(D_MODEL / 256, 32);
        gemv4_splitk<16><<<grd, blk, 0, stream>>>(zH, W_mem, mem, D_H, D_MODEL);
    }
    // Stage 2: V = mem @ W_v      (K=2048, 32 slices x 64)
    {
        dim3 grd(D_MODEL / 256, 32);
        gemv4_splitk<64><<<grd, blk, 0, stream>>>(mem, W_v, V, D_MODEL, D_MODEL);
    }
    // Stage 3: r = V @ W_o        (K=2048, 32 slices x 64)
    {
        dim3 grd(D_MODEL / 256, 32);
        gemv4_splitk<64><<<grd, blk, 0, stream>>>(V, W_o, r, D_MODEL, D_MODEL);
    }
    // Stage 4: out = lh + sigmoid(gate) * r  (broadcast over T)
    {
        long chunks = (long)B_ * T_ * D_MODEL / 4;   // 8,388,608
        dim3 grd((unsigned)(chunks / 256));          // exact multiple
        broadcast_add<<<grd, blk, 0, stream>>>(
            (const vfloat4*)lh, r, gate, (vfloat4*)out);
    }
}